// Round 1
// baseline (1905.102 us; speedup 1.0000x reference)
//
#include <hip/hip_runtime.h>
#include <hip/hip_bf16.h>
#include <math.h>

// ECE/MCE: per-row softmax confidence + argmax accuracy, equal-mass 20-bin
// calibration error. Sort-free: two-level counting rank on float-bit keys.

#define N_ROWS   260000
#define N_COLS   1024
#define N_BINS   20
#define BIN_SIZE 13000
#define N_BOUND  19            // interior boundaries at ranks 13000*k
#define KEY_BIAS 0x3A800000u   // bits of 2^-10 (min possible confidence)
#define KEY_MAX  0x04FFFFFF    // bits(1.0)-KEY_BIAS-1 clamp
#define SUB_SHIFT 11
#define N_BUCKETS 40960        // 0x05000000 >> 11
#define N_SUB     2048         // low 11 bits -> sub-bucket == exact fp32 key

__device__ __forceinline__ int conf_key(float c) {
    unsigned key = __float_as_uint(c);
    int adj = (int)(key - KEY_BIAS);
    adj = adj < 0 ? 0 : adj;
    adj = adj > KEY_MAX ? KEY_MAX : adj;
    return adj;
}

// ---- K1: one wave per row: max/argmax + sum(exp) + histogram atomics ----
__global__ __launch_bounds__(256) void k_rowstats(
    const float* __restrict__ logits, const int* __restrict__ labels,
    float* __restrict__ conf, float* __restrict__ accf,
    unsigned* __restrict__ histCnt, float* __restrict__ histConf,
    float* __restrict__ histAcc)
{
    const int wave = threadIdx.x >> 6;
    const int lane = threadIdx.x & 63;
    const int row  = blockIdx.x * 4 + wave;

    const float4* rowp = (const float4*)(logits + (size_t)row * N_COLS);
    float4 vals[4];
    float bv = -INFINITY; int bi = 0;
#pragma unroll
    for (int k = 0; k < 4; ++k) {
        float4 v = rowp[k * 64 + lane];
        vals[k] = v;
        int base = 4 * (k * 64 + lane);
        if (v.x > bv) { bv = v.x; bi = base + 0; }
        if (v.y > bv) { bv = v.y; bi = base + 1; }
        if (v.z > bv) { bv = v.z; bi = base + 2; }
        if (v.w > bv) { bv = v.w; bi = base + 3; }
    }
    // wave argmax (max value, min index on ties == first occurrence)
#pragma unroll
    for (int off = 32; off > 0; off >>= 1) {
        float ov = __shfl_xor(bv, off, 64);
        int   oi = __shfl_xor(bi, off, 64);
        if (ov > bv || (ov == bv && oi < bi)) { bv = ov; bi = oi; }
    }
    float s = 0.f;
#pragma unroll
    for (int k = 0; k < 4; ++k) {
        s += __expf(vals[k].x - bv) + __expf(vals[k].y - bv)
           + __expf(vals[k].z - bv) + __expf(vals[k].w - bv);
    }
#pragma unroll
    for (int off = 32; off > 0; off >>= 1)
        s += __shfl_xor(s, off, 64);

    if (lane == 0) {
        float c = 1.0f / s;                      // max softmax = exp(0)/s
        float a = (bi == labels[row]) ? 1.0f : 0.0f;
        conf[row] = c;
        accf[row] = a;
        int bucket = conf_key(c) >> SUB_SHIFT;
        atomicAdd(&histCnt[bucket], 1u);
        atomicAdd(&histConf[bucket], c);
        atomicAdd(&histAcc[bucket], a);
    }
}

// ---- K2: single-block scan over buckets; locate the 19 boundary ranks ----
__global__ __launch_bounds__(1024) void k_scan(
    const unsigned* __restrict__ histCnt, const float* __restrict__ histConf,
    const float* __restrict__ histAcc,
    int* __restrict__ bBucket, int* __restrict__ bNeed,
    double* __restrict__ bBaseC, double* __restrict__ bBaseA,
    double* __restrict__ tot)
{
    __shared__ unsigned sN[1024];
    __shared__ double   sC[1024];
    __shared__ double   sA[1024];
    __shared__ unsigned carryN;
    __shared__ double   carryC, carryA;
    const int t = threadIdx.x;
    if (t == 0) { carryN = 0; carryC = 0.0; carryA = 0.0; }
    __syncthreads();

    for (int chunk = 0; chunk < N_BUCKETS / 1024; ++chunk) {
        int i = chunk * 1024 + t;
        unsigned n = histCnt[i];
        double c = (double)histConf[i];
        double a = (double)histAcc[i];
        sN[t] = n; sC[t] = c; sA[t] = a;
        __syncthreads();
        // Hillis-Steele inclusive scan
        for (int off = 1; off < 1024; off <<= 1) {
            unsigned n2 = 0; double c2 = 0, a2 = 0;
            if (t >= off) { n2 = sN[t - off]; c2 = sC[t - off]; a2 = sA[t - off]; }
            __syncthreads();
            sN[t] += n2; sC[t] += c2; sA[t] += a2;
            __syncthreads();
        }
        unsigned inclN = carryN + sN[t];
        unsigned exclN = inclN - n;
        double   exclC = carryC + sC[t] - c;
        double   exclA = carryA + sA[t] - a;
        for (int k = 0; k < N_BOUND; ++k) {
            unsigned r = (unsigned)BIN_SIZE * (k + 1);
            if (exclN < r && r <= inclN) {
                bBucket[k] = i;
                bNeed[k]   = (int)(r - exclN);   // >= 1
                bBaseC[k]  = exclC;
                bBaseA[k]  = exclA;
            }
        }
        __syncthreads();
        if (t == 1023) { carryN += sN[1023]; carryC += sC[1023]; carryA += sA[1023]; }
        __syncthreads();
    }
    if (t == 0) { tot[0] = carryC; tot[1] = carryA; }
}

// ---- K3: sub-histogram (exact key) for elements in boundary buckets ----
__global__ __launch_bounds__(256) void k_subhist(
    const float* __restrict__ conf, const float* __restrict__ accf,
    const int* __restrict__ bBucket,
    unsigned* __restrict__ subCnt, float* __restrict__ subConf,
    float* __restrict__ subAcc, int n)
{
    __shared__ int sB[N_BOUND];
    if (threadIdx.x < N_BOUND) sB[threadIdx.x] = bBucket[threadIdx.x];
    __syncthreads();
    for (int i = blockIdx.x * blockDim.x + threadIdx.x; i < n;
         i += gridDim.x * blockDim.x) {
        float cv = conf[i];
        int adj = conf_key(cv);
        int bucket = adj >> SUB_SHIFT;
        int low = adj & (N_SUB - 1);
        float av = accf[i];
#pragma unroll
        for (int k = 0; k < N_BOUND; ++k) {
            if (bucket == sB[k]) {
                atomicAdd(&subCnt[k * N_SUB + low], 1u);
                atomicAdd(&subConf[k * N_SUB + low], cv);
                atomicAdd(&subAcc[k * N_SUB + low], av);
            }
        }
    }
}

// ---- K4: finalize: split boundary buckets, form bins, write (ece, mce) ----
__global__ __launch_bounds__(64) void k_final(
    const int* __restrict__ bNeed,
    const double* __restrict__ bBaseC, const double* __restrict__ bBaseA,
    const unsigned* __restrict__ subCnt, const float* __restrict__ subConf,
    const float* __restrict__ subAcc,
    const double* __restrict__ tot, float* __restrict__ out)
{
    __shared__ double pC[N_BINS + 1], pA[N_BINS + 1];
    const int t = threadIdx.x;
    if (t < N_BOUND) {
        int need = bNeed[t];
        const unsigned* sc = subCnt  + t * N_SUB;
        const float*    sf = subConf + t * N_SUB;
        const float*    sa = subAcc  + t * N_SUB;
        double lc = 0, la = 0; int cnt = 0;
        for (int s = 0; s < N_SUB; ++s) {
            int c = (int)sc[s];
            if (c == 0) continue;
            if (cnt + c <= need) {
                lc += (double)sf[s]; la += (double)sa[s]; cnt += c;
                if (cnt == need) break;
            } else {
                // exact-fp32-tie group straddles the boundary: apportion.
                double frac = (double)(need - cnt) / (double)c;
                lc += (double)sf[s] * frac; la += (double)sa[s] * frac;
                break;
            }
        }
        pC[t + 1] = bBaseC[t] + lc;
        pA[t + 1] = bBaseA[t] + la;
    }
    if (t == 0) { pC[0] = 0.0; pA[0] = 0.0; pC[N_BINS] = tot[0]; pA[N_BINS] = tot[1]; }
    __syncthreads();
    if (t == 0) {
        double ece = 0.0, mce = 0.0;
        for (int b = 0; b < N_BINS; ++b) {
            double ce = fabs((pC[b + 1] - pC[b]) - (pA[b + 1] - pA[b]))
                        / (double)BIN_SIZE;
            ece += ce;
            if (ce > mce) mce = ce;
        }
        out[0] = (float)(ece / (double)N_BINS);
        out[1] = (float)mce;
    }
}

extern "C" void kernel_launch(void* const* d_in, const int* in_sizes, int n_in,
                              void* d_out, int out_size, void* d_ws, size_t ws_size,
                              hipStream_t stream)
{
    const float* logits = (const float*)d_in[0];
    const int*   labels = (const int*)d_in[1];
    float* out = (float*)d_out;

    char* ws = (char*)d_ws;
    size_t off = 0;
    auto alloc = [&](size_t bytes) -> void* {
        void* p = ws + off;
        off = (off + bytes + 255) & ~(size_t)255;
        return p;
    };
    float*    conf     = (float*)alloc((size_t)N_ROWS * 4);
    float*    accf     = (float*)alloc((size_t)N_ROWS * 4);
    char*     zbase    = ws + off;                 // zeroed region start
    unsigned* histCnt  = (unsigned*)alloc((size_t)N_BUCKETS * 4);
    float*    histConf = (float*)alloc((size_t)N_BUCKETS * 4);
    float*    histAcc  = (float*)alloc((size_t)N_BUCKETS * 4);
    unsigned* subCnt   = (unsigned*)alloc((size_t)N_BOUND * N_SUB * 4);
    float*    subConf  = (float*)alloc((size_t)N_BOUND * N_SUB * 4);
    float*    subAcc   = (float*)alloc((size_t)N_BOUND * N_SUB * 4);
    size_t    zbytes   = (size_t)((ws + off) - zbase);
    int*      bBucket  = (int*)alloc(N_BOUND * 4);
    int*      bNeed    = (int*)alloc(N_BOUND * 4);
    double*   bBaseC   = (double*)alloc(N_BOUND * 8);
    double*   bBaseA   = (double*)alloc(N_BOUND * 8);
    double*   tot      = (double*)alloc(16);

    hipMemsetAsync(zbase, 0, zbytes, stream);
    k_rowstats<<<N_ROWS / 4, 256, 0, stream>>>(logits, labels, conf, accf,
                                               histCnt, histConf, histAcc);
    k_scan<<<1, 1024, 0, stream>>>(histCnt, histConf, histAcc,
                                   bBucket, bNeed, bBaseC, bBaseA, tot);
    k_subhist<<<512, 256, 0, stream>>>(conf, accf, bBucket,
                                       subCnt, subConf, subAcc, N_ROWS);
    k_final<<<1, 64, 0, stream>>>(bNeed, bBaseC, bBaseA,
                                  subCnt, subConf, subAcc, tot, out);
}

// Round 2
// 1366.373 us; speedup vs baseline: 1.3943x; 1.3943x over previous
//
#include <hip/hip_runtime.h>
#include <hip/hip_bf16.h>
#include <math.h>

// ECE/MCE: per-row softmax confidence + argmax accuracy, equal-mass 20-bin
// calibration error. Sort-free: two-level counting rank on float-bit keys.

#define N_ROWS   260000
#define N_COLS   1024
#define N_BINS   20
#define BIN_SIZE 13000
#define N_BOUND  19            // interior boundaries at ranks 13000*k
#define KEY_BIAS 0x3A800000u   // bits of 2^-10 (min possible confidence)
#define KEY_MAX  0x04FFFFFF    // bits(1.0)-KEY_BIAS-1 clamp
#define SUB_SHIFT 11
#define N_BUCKETS 40960        // 0x05000000 >> 11
#define N_SUB     2048         // low 11 bits -> sub-bucket == exact fp32 key

__device__ __forceinline__ int conf_key(float c) {
    unsigned key = __float_as_uint(c);
    int adj = (int)(key - KEY_BIAS);
    adj = adj < 0 ? 0 : adj;
    adj = adj > KEY_MAX ? KEY_MAX : adj;
    return adj;
}

// ---- K1: one wave per row: max/argmax + sum(exp) + histogram atomics ----
__global__ __launch_bounds__(256) void k_rowstats(
    const float* __restrict__ logits, const int* __restrict__ labels,
    float* __restrict__ conf, float* __restrict__ accf,
    unsigned* __restrict__ histCnt, float* __restrict__ histConf,
    float* __restrict__ histAcc)
{
    const int wave = threadIdx.x >> 6;
    const int lane = threadIdx.x & 63;
    const int row  = blockIdx.x * 4 + wave;

    const float4* rowp = (const float4*)(logits + (size_t)row * N_COLS);
    float4 vals[4];
    float bv = -INFINITY; int bi = 0;
#pragma unroll
    for (int k = 0; k < 4; ++k) {
        float4 v = rowp[k * 64 + lane];
        vals[k] = v;
        int base = 4 * (k * 64 + lane);
        if (v.x > bv) { bv = v.x; bi = base + 0; }
        if (v.y > bv) { bv = v.y; bi = base + 1; }
        if (v.z > bv) { bv = v.z; bi = base + 2; }
        if (v.w > bv) { bv = v.w; bi = base + 3; }
    }
    // wave argmax (max value, min index on ties == first occurrence)
#pragma unroll
    for (int off = 32; off > 0; off >>= 1) {
        float ov = __shfl_xor(bv, off, 64);
        int   oi = __shfl_xor(bi, off, 64);
        if (ov > bv || (ov == bv && oi < bi)) { bv = ov; bi = oi; }
    }
    float s = 0.f;
#pragma unroll
    for (int k = 0; k < 4; ++k) {
        s += __expf(vals[k].x - bv) + __expf(vals[k].y - bv)
           + __expf(vals[k].z - bv) + __expf(vals[k].w - bv);
    }
#pragma unroll
    for (int off = 32; off > 0; off >>= 1)
        s += __shfl_xor(s, off, 64);

    if (lane == 0) {
        float c = 1.0f / s;                      // max softmax = exp(0)/s
        float a = (bi == labels[row]) ? 1.0f : 0.0f;
        conf[row] = c;
        accf[row] = a;
        int bucket = conf_key(c) >> SUB_SHIFT;
        atomicAdd(&histCnt[bucket], 1u);
        atomicAdd(&histConf[bucket], c);
        atomicAdd(&histAcc[bucket], a);
    }
}

// ---- K2: single block; each thread owns 40 consecutive buckets.
// Serial local accumulate -> one 1024-wide LDS scan -> local boundary walk.
__global__ __launch_bounds__(1024) void k_scan(
    const unsigned* __restrict__ histCnt, const float* __restrict__ histConf,
    const float* __restrict__ histAcc,
    int* __restrict__ bBucket, int* __restrict__ bNeed,
    double* __restrict__ bBaseC, double* __restrict__ bBaseA,
    double* __restrict__ tot)
{
    const int PER = N_BUCKETS / 1024;   // 40
    const int t = threadIdx.x;
    const int base = t * PER;

    unsigned n = 0; double c = 0.0, a = 0.0;
#pragma unroll 8
    for (int j = 0; j < PER; ++j) {
        n += histCnt[base + j];
        c += (double)histConf[base + j];
        a += (double)histAcc[base + j];
    }
    __shared__ unsigned sN[1024];
    __shared__ double   sC[1024];
    __shared__ double   sA[1024];
    sN[t] = n; sC[t] = c; sA[t] = a;
    __syncthreads();
    for (int off = 1; off < 1024; off <<= 1) {
        unsigned n2 = 0; double c2 = 0, a2 = 0;
        if (t >= off) { n2 = sN[t - off]; c2 = sC[t - off]; a2 = sA[t - off]; }
        __syncthreads();
        sN[t] += n2; sC[t] += c2; sA[t] += a2;
        __syncthreads();
    }
    unsigned exclN = sN[t] - n;          // exclusive prefix at this thread's range
    double   exclC = sC[t] - c;
    double   exclA = sA[t] - a;

    for (int j = 0; j < PER; ++j) {
        unsigned bn = histCnt[base + j];
        if (bn == 0) continue;
        double bc = (double)histConf[base + j];
        double ba = (double)histAcc[base + j];
        unsigned incl = exclN + bn;
        unsigned r = (exclN / BIN_SIZE + 1) * BIN_SIZE;
        while (r <= incl && r < (unsigned)N_ROWS) {
            int k = (int)(r / BIN_SIZE) - 1;     // 0..18
            bBucket[k] = base + j;
            bNeed[k]   = (int)(r - exclN);       // >= 1
            bBaseC[k]  = exclC;
            bBaseA[k]  = exclA;
            r += BIN_SIZE;
        }
        exclN = incl; exclC += bc; exclA += ba;
    }
    if (t == 1023) { tot[0] = sC[1023]; tot[1] = sA[1023]; }
}

// ---- K3: sub-histogram (exact key) for elements in boundary buckets ----
__global__ __launch_bounds__(256) void k_subhist(
    const float* __restrict__ conf, const float* __restrict__ accf,
    const int* __restrict__ bBucket,
    unsigned* __restrict__ subCnt, float* __restrict__ subConf,
    float* __restrict__ subAcc, int n)
{
    __shared__ int sB[N_BOUND];
    if (threadIdx.x < N_BOUND) sB[threadIdx.x] = bBucket[threadIdx.x];
    __syncthreads();
    for (int i = blockIdx.x * blockDim.x + threadIdx.x; i < n;
         i += gridDim.x * blockDim.x) {
        float cv = conf[i];
        int adj = conf_key(cv);
        int bucket = adj >> SUB_SHIFT;
        int low = adj & (N_SUB - 1);
        float av = accf[i];
#pragma unroll
        for (int k = 0; k < N_BOUND; ++k) {
            if (bucket == sB[k]) {
                atomicAdd(&subCnt[k * N_SUB + low], 1u);
                atomicAdd(&subConf[k * N_SUB + low], cv);
                atomicAdd(&subAcc[k * N_SUB + low], av);
            }
        }
    }
}

// ---- K4: one block per boundary: block-parallel split of the boundary
// bucket's 2048 exact-key sub-buckets (fractional tie apportioning kept).
__global__ __launch_bounds__(256) void k_split(
    const int* __restrict__ bNeed,
    const double* __restrict__ bBaseC, const double* __restrict__ bBaseA,
    const unsigned* __restrict__ subCnt, const float* __restrict__ subConf,
    const float* __restrict__ subAcc,
    double* __restrict__ binC, double* __restrict__ binA)
{
    const int k = blockIdx.x;      // 0..18
    const int t = threadIdx.x;     // 0..255, 8 sub-buckets each
    const unsigned* sc = subCnt  + k * N_SUB;
    const float*    sf = subConf + k * N_SUB;
    const float*    sa = subAcc  + k * N_SUB;
    const unsigned need = (unsigned)bNeed[k];

    unsigned c8[8];
    unsigned loc = 0;
#pragma unroll
    for (int j = 0; j < 8; ++j) { c8[j] = sc[t * 8 + j]; loc += c8[j]; }

    __shared__ unsigned sCnt[256];
    sCnt[t] = loc;
    __syncthreads();
    for (int off = 1; off < 256; off <<= 1) {
        unsigned v = (t >= off) ? sCnt[t - off] : 0u;
        __syncthreads();
        sCnt[t] += v;
        __syncthreads();
    }
    unsigned running = sCnt[t] - loc;    // exclusive prefix of counts

    double myC = 0.0, myA = 0.0;
#pragma unroll
    for (int j = 0; j < 8; ++j) {
        unsigned cj = c8[j];
        if (cj == 0) continue;
        if (running + cj <= need) {
            myC += (double)sf[t * 8 + j];
            myA += (double)sa[t * 8 + j];
        } else if (running < need) {
            double frac = (double)(need - running) / (double)cj;
            myC += frac * (double)sf[t * 8 + j];
            myA += frac * (double)sa[t * 8 + j];
        }
        running += cj;
    }
    __shared__ double rC[256], rA[256];
    rC[t] = myC; rA[t] = myA;
    __syncthreads();
    for (int off = 128; off > 0; off >>= 1) {
        if (t < off) { rC[t] += rC[t + off]; rA[t] += rA[t + off]; }
        __syncthreads();
    }
    if (t == 0) {
        binC[k] = bBaseC[k] + rC[0];     // cumulative sums at rank 13000*(k+1)
        binA[k] = bBaseA[k] + rA[0];
    }
}

// ---- K5: tiny finalize -> (ece, mce) ----
__global__ __launch_bounds__(64) void k_final(
    const double* __restrict__ binC, const double* __restrict__ binA,
    const double* __restrict__ tot, float* __restrict__ out)
{
    if (threadIdx.x == 0) {
        double pC[N_BINS + 1], pA[N_BINS + 1];
        pC[0] = 0.0; pA[0] = 0.0;
        for (int k = 0; k < N_BOUND; ++k) { pC[k + 1] = binC[k]; pA[k + 1] = binA[k]; }
        pC[N_BINS] = tot[0]; pA[N_BINS] = tot[1];
        double ece = 0.0, mce = 0.0;
        for (int b = 0; b < N_BINS; ++b) {
            double ce = fabs((pC[b + 1] - pC[b]) - (pA[b + 1] - pA[b]))
                        / (double)BIN_SIZE;
            ece += ce;
            if (ce > mce) mce = ce;
        }
        out[0] = (float)(ece / (double)N_BINS);
        out[1] = (float)mce;
    }
}

extern "C" void kernel_launch(void* const* d_in, const int* in_sizes, int n_in,
                              void* d_out, int out_size, void* d_ws, size_t ws_size,
                              hipStream_t stream)
{
    const float* logits = (const float*)d_in[0];
    const int*   labels = (const int*)d_in[1];
    float* out = (float*)d_out;

    char* ws = (char*)d_ws;
    size_t off = 0;
    auto alloc = [&](size_t bytes) -> void* {
        void* p = ws + off;
        off = (off + bytes + 255) & ~(size_t)255;
        return p;
    };
    float*    conf     = (float*)alloc((size_t)N_ROWS * 4);
    float*    accf     = (float*)alloc((size_t)N_ROWS * 4);
    char*     zbase    = ws + off;                 // zeroed region start
    unsigned* histCnt  = (unsigned*)alloc((size_t)N_BUCKETS * 4);
    float*    histConf = (float*)alloc((size_t)N_BUCKETS * 4);
    float*    histAcc  = (float*)alloc((size_t)N_BUCKETS * 4);
    unsigned* subCnt   = (unsigned*)alloc((size_t)N_BOUND * N_SUB * 4);
    float*    subConf  = (float*)alloc((size_t)N_BOUND * N_SUB * 4);
    float*    subAcc   = (float*)alloc((size_t)N_BOUND * N_SUB * 4);
    size_t    zbytes   = (size_t)((ws + off) - zbase);
    int*      bBucket  = (int*)alloc(N_BOUND * 4);
    int*      bNeed    = (int*)alloc(N_BOUND * 4);
    double*   bBaseC   = (double*)alloc(N_BOUND * 8);
    double*   bBaseA   = (double*)alloc(N_BOUND * 8);
    double*   binC     = (double*)alloc(N_BOUND * 8);
    double*   binA     = (double*)alloc(N_BOUND * 8);
    double*   tot      = (double*)alloc(16);

    hipMemsetAsync(zbase, 0, zbytes, stream);
    k_rowstats<<<N_ROWS / 4, 256, 0, stream>>>(logits, labels, conf, accf,
                                               histCnt, histConf, histAcc);
    k_scan<<<1, 1024, 0, stream>>>(histCnt, histConf, histAcc,
                                   bBucket, bNeed, bBaseC, bBaseA, tot);
    k_subhist<<<512, 256, 0, stream>>>(conf, accf, bBucket,
                                       subCnt, subConf, subAcc, N_ROWS);
    k_split<<<N_BOUND, 256, 0, stream>>>(bNeed, bBaseC, bBaseA,
                                         subCnt, subConf, subAcc, binC, binA);
    k_final<<<1, 64, 0, stream>>>(binC, binA, tot, out);
}